// Round 1
// baseline (793.984 us; speedup 1.0000x reference)
//
#include <hip/hip_runtime.h>

#define T_STEPS 256
#define BATCH   1000
#define D_IN    300
#define H4      8

// ---------------------------------------------------------------------------
// Kernel A: xg0[t,b,g] = sum_d x[t,b,d] * W_ih0[g,d] + b_ih0[g] + b_hh0[g]
// Lane mapping: idx = row*8 + g. The 8 lanes of a row share the x float4 load
// (HW broadcast), so x is fetched exactly once; output store is coalesced.
// HBM-bound: ~307 MB read @ ~6 TB/s.
// ---------------------------------------------------------------------------
__global__ __launch_bounds__(256) void xproj_kernel(
    const float* __restrict__ x, const float* __restrict__ W,
    const float* __restrict__ b_ih, const float* __restrict__ b_hh,
    float* __restrict__ xg)
{
    int idx = blockIdx.x * 256 + threadIdx.x;   // row*8 + g
    int row = idx >> 3;
    int g   = idx & 7;
    if (row >= T_STEPS * BATCH) return;

    const float4* __restrict__ xr = (const float4*)(x + (long)row * D_IN);
    const float4* __restrict__ wr = (const float4*)(W + g * D_IN);

    float a0 = 0.f, a1 = 0.f, a2 = 0.f, a3 = 0.f;
#pragma unroll 5
    for (int k = 0; k < D_IN / 4; ++k) {        // 75 float4 pairs
        float4 xv = xr[k];
        float4 wv = wr[k];
        a0 += xv.x * wv.x;
        a1 += xv.y * wv.y;
        a2 += xv.z * wv.z;
        a3 += xv.w * wv.w;
    }
    xg[idx] = (a0 + a1) + (a2 + a3) + b_ih[g] + b_hh[g];
}

// ---------------------------------------------------------------------------
// Kernel B: the sequential 2-layer LSTM scan + final linear.
// H=2 -> one thread per batch element; all recurrent weights + state live in
// registers. xg0 reads are software-pipelined depth 4 to hide latency.
// ---------------------------------------------------------------------------
__device__ __forceinline__ float sigf(float x) {
    return 1.0f / (1.0f + __expf(-x));
}
__device__ __forceinline__ float tanhfast(float x) {
    // 1 - 2/(e^{2x}+1); exact limits at +-inf, abs err ~1e-7
    return 1.0f - 2.0f / (__expf(2.0f * x) + 1.0f);
}

__global__ __launch_bounds__(64) void lstm_seq_kernel(
    const float* __restrict__ xg,
    const float* __restrict__ h0in, const float* __restrict__ c0in,
    const float* __restrict__ Whh0, const float* __restrict__ Wih1,
    const float* __restrict__ Whh1, const float* __restrict__ bih1,
    const float* __restrict__ bhh1, const float* __restrict__ Wlin,
    const float* __restrict__ blin, float* __restrict__ out)
{
    int b = blockIdx.x * 64 + threadIdx.x;
    bool active = (b < BATCH);
    int bb = active ? b : (BATCH - 1);   // clamp: harmless compute, no store

    // Tiny weights -> registers (wave-uniform addresses, broadcast loads)
    float whh0[H4][2], wih1[H4][2], whh1[H4][2], bias1[H4];
#pragma unroll
    for (int k = 0; k < H4; ++k) {
        whh0[k][0] = Whh0[2 * k]; whh0[k][1] = Whh0[2 * k + 1];
        wih1[k][0] = Wih1[2 * k]; wih1[k][1] = Wih1[2 * k + 1];
        whh1[k][0] = Whh1[2 * k]; whh1[k][1] = Whh1[2 * k + 1];
        bias1[k]   = bih1[k] + bhh1[k];
    }

    // Initial state (layer 0 then layer 1); inputs are [LAYERS, B, H]
    float h0a = h0in[2 * bb],             h0b = h0in[2 * bb + 1];
    float c0a = c0in[2 * bb],             c0b = c0in[2 * bb + 1];
    float h1a = h0in[2 * BATCH + 2 * bb], h1b = h0in[2 * BATCH + 2 * bb + 1];
    float c1a = c0in[2 * BATCH + 2 * bb], c1b = c0in[2 * BATCH + 2 * bb + 1];

    const float4* __restrict__ xp = (const float4*)xg;

    // depth-4 software pipeline on the per-step gate loads (32 B/step)
    float4 plo[4], phi[4];
#pragma unroll
    for (int t = 0; t < 4; ++t) {
        plo[t] = xp[(t * BATCH + bb) * 2];
        phi[t] = xp[(t * BATCH + bb) * 2 + 1];
    }

#pragma unroll 4
    for (int t = 0; t < T_STEPS; ++t) {
        int s = t & 3;
        float4 l4 = plo[s], h4 = phi[s];
        if (t + 4 < T_STEPS) {
            plo[s] = xp[((t + 4) * BATCH + bb) * 2];
            phi[s] = xp[((t + 4) * BATCH + bb) * 2 + 1];
        }

        // ----- layer 0: gates = xg + h @ Whh0^T  (order: i,f,g,o pairs) ----
        float g0 = l4.x + h0a * whh0[0][0] + h0b * whh0[0][1];
        float g1 = l4.y + h0a * whh0[1][0] + h0b * whh0[1][1];
        float g2 = l4.z + h0a * whh0[2][0] + h0b * whh0[2][1];
        float g3 = l4.w + h0a * whh0[3][0] + h0b * whh0[3][1];
        float g4 = h4.x + h0a * whh0[4][0] + h0b * whh0[4][1];
        float g5 = h4.y + h0a * whh0[5][0] + h0b * whh0[5][1];
        float g6 = h4.z + h0a * whh0[6][0] + h0b * whh0[6][1];
        float g7 = h4.w + h0a * whh0[7][0] + h0b * whh0[7][1];
        c0a = sigf(g2) * c0a + sigf(g0) * tanhfast(g4);
        c0b = sigf(g3) * c0b + sigf(g1) * tanhfast(g5);
        h0a = sigf(g6) * tanhfast(c0a);
        h0b = sigf(g7) * tanhfast(c0b);

        // ----- layer 1 ------------------------------------------------------
        float q0 = bias1[0] + h0a * wih1[0][0] + h0b * wih1[0][1]
                            + h1a * whh1[0][0] + h1b * whh1[0][1];
        float q1 = bias1[1] + h0a * wih1[1][0] + h0b * wih1[1][1]
                            + h1a * whh1[1][0] + h1b * whh1[1][1];
        float q2 = bias1[2] + h0a * wih1[2][0] + h0b * wih1[2][1]
                            + h1a * whh1[2][0] + h1b * whh1[2][1];
        float q3 = bias1[3] + h0a * wih1[3][0] + h0b * wih1[3][1]
                            + h1a * whh1[3][0] + h1b * whh1[3][1];
        float q4 = bias1[4] + h0a * wih1[4][0] + h0b * wih1[4][1]
                            + h1a * whh1[4][0] + h1b * whh1[4][1];
        float q5 = bias1[5] + h0a * wih1[5][0] + h0b * wih1[5][1]
                            + h1a * whh1[5][0] + h1b * whh1[5][1];
        float q6 = bias1[6] + h0a * wih1[6][0] + h0b * wih1[6][1]
                            + h1a * whh1[6][0] + h1b * whh1[6][1];
        float q7 = bias1[7] + h0a * wih1[7][0] + h0b * wih1[7][1]
                            + h1a * whh1[7][0] + h1b * whh1[7][1];
        c1a = sigf(q2) * c1a + sigf(q0) * tanhfast(q4);
        c1b = sigf(q3) * c1b + sigf(q1) * tanhfast(q5);
        h1a = sigf(q6) * tanhfast(c1a);
        h1b = sigf(q7) * tanhfast(c1b);
    }

    if (active)
        out[b] = h1a * Wlin[0] + h1b * Wlin[1] + blin[0];
}

extern "C" void kernel_launch(void* const* d_in, const int* in_sizes, int n_in,
                              void* d_out, int out_size, void* d_ws, size_t ws_size,
                              hipStream_t stream) {
    const float* x      = (const float*)d_in[0];
    const float* h0     = (const float*)d_in[1];
    const float* c0     = (const float*)d_in[2];
    const float* W_ih0  = (const float*)d_in[3];
    const float* W_hh0  = (const float*)d_in[4];
    const float* b_ih0  = (const float*)d_in[5];
    const float* b_hh0  = (const float*)d_in[6];
    const float* W_ih1  = (const float*)d_in[7];
    const float* W_hh1  = (const float*)d_in[8];
    const float* b_ih1  = (const float*)d_in[9];
    const float* b_hh1  = (const float*)d_in[10];
    const float* W_lin  = (const float*)d_in[11];
    const float* b_lin  = (const float*)d_in[12];
    float* out = (float*)d_out;
    float* xg  = (float*)d_ws;   // T*B*8 floats = 8.192 MB

    const int rows  = T_STEPS * BATCH;          // 256000
    const int total = rows * H4;                // 2048000 -> 8000 blocks
    xproj_kernel<<<total / 256, 256, 0, stream>>>(x, W_ih0, b_ih0, b_hh0, xg);
    lstm_seq_kernel<<<(BATCH + 63) / 64, 64, 0, stream>>>(
        xg, h0, c0, W_hh0, W_ih1, W_hh1, b_ih1, b_hh1, W_lin, b_lin, out);
}

// Round 3
// 580.780 us; speedup vs baseline: 1.3671x; 1.3671x over previous
//
#include <hip/hip_runtime.h>

#define T_STEPS 256
#define BATCH   1000
#define D_IN    300
#define H4      8
#define ROWS_PER_BLK 32

// ---------------------------------------------------------------------------
// Kernel A: xg0[row,g] = dot(x[row,:], W_ih0[g,:]) + b_ih0[g] + b_hh0[g]
// Block = 256 threads stages 32 contiguous rows (38.4 KB) + W (9.6 KB) into
// LDS with perfectly-coalesced float4 loads (tile is one contiguous region),
// then thread (r,g)=(tid>>3,tid&7) does the 300-MAC dot from LDS.
// LDS bank check: x read addr r*300+4k -> bank (12r+4k)%32, r=0..7 distinct,
// covers all 32 banks once/wave; 8-lane same-address groups broadcast (free).
// ---------------------------------------------------------------------------
__global__ __launch_bounds__(256) void xproj_kernel(
    const float* __restrict__ x, const float* __restrict__ W,
    const float* __restrict__ b_ih, const float* __restrict__ b_hh,
    float* __restrict__ xg)
{
    __shared__ __align__(16) float xs[ROWS_PER_BLK * D_IN];  // 38.4 KB
    __shared__ __align__(16) float ws[H4 * D_IN];            //  9.6 KB

    const int tid = threadIdx.x;

    // Stage x tile: 32*300 = 9600 floats = 2400 float4, contiguous in HBM.
    const float4* __restrict__ xin = (const float4*)(x + (long)blockIdx.x * (ROWS_PER_BLK * D_IN));
    float4* xs4 = (float4*)xs;
    for (int k = tid; k < ROWS_PER_BLK * D_IN / 4; k += 256)
        xs4[k] = xin[k];

    // Stage W: 8*300 = 2400 floats = 600 float4.
    const float4* __restrict__ win = (const float4*)W;
    float4* ws4 = (float4*)ws;
    for (int k = tid; k < H4 * D_IN / 4; k += 256)
        ws4[k] = win[k];

    __syncthreads();

    const int r = tid >> 3;
    const int g = tid & 7;
    const float4* __restrict__ xr = (const float4*)(xs + r * D_IN);
    const float4* __restrict__ wr = (const float4*)(ws + g * D_IN);

    float a0 = 0.f, a1 = 0.f, a2 = 0.f, a3 = 0.f;
#pragma unroll 5
    for (int k = 0; k < D_IN / 4; ++k) {      // 75 float4 pairs
        float4 xv = xr[k];
        float4 wv = wr[k];
        a0 += xv.x * wv.x;
        a1 += xv.y * wv.y;
        a2 += xv.z * wv.z;
        a3 += xv.w * wv.w;
    }
    // out index = ((blk*32 + r)*8 + g) = blk*256 + tid  -> coalesced
    xg[(long)blockIdx.x * 256 + tid] = (a0 + a1) + (a2 + a3) + b_ih[g] + b_hh[g];
}

// ---------------------------------------------------------------------------
// Kernel B: sequential 2-layer LSTM scan + final linear.
// One thread per batch element (H=2 -> all weights/state in registers).
// Activations use raw v_exp_f32 + v_rcp_f32 (no IEEE-divide expansion).
// Layer-1 gate pre-activation (h1-dependent half) is hoisted to the end of
// the previous step for cross-layer ILP.
// ---------------------------------------------------------------------------
__device__ __forceinline__ float sigf(float x) {
    return __builtin_amdgcn_rcpf(1.0f + __expf(-x));       // neg+exp+add+rcp
}
__device__ __forceinline__ float tanhfast(float x) {
    // 1 - 2/(e^{2x}+1); exact limits at +-inf
    return fmaf(-2.0f, __builtin_amdgcn_rcpf(1.0f + __expf(2.0f * x)), 1.0f);
}

__global__ __launch_bounds__(64) void lstm_seq_kernel(
    const float* __restrict__ xg,
    const float* __restrict__ h0in, const float* __restrict__ c0in,
    const float* __restrict__ Whh0, const float* __restrict__ Wih1,
    const float* __restrict__ Whh1, const float* __restrict__ bih1,
    const float* __restrict__ bhh1, const float* __restrict__ Wlin,
    const float* __restrict__ blin, float* __restrict__ out)
{
    int b = blockIdx.x * 64 + threadIdx.x;
    bool active = (b < BATCH);
    int bb = active ? b : (BATCH - 1);   // clamp: harmless compute, no store

    // Tiny weights -> registers (wave-uniform addresses, broadcast loads)
    float whh0[H4][2], wih1[H4][2], whh1[H4][2], bias1[H4];
#pragma unroll
    for (int k = 0; k < H4; ++k) {
        whh0[k][0] = Whh0[2 * k]; whh0[k][1] = Whh0[2 * k + 1];
        wih1[k][0] = Wih1[2 * k]; wih1[k][1] = Wih1[2 * k + 1];
        whh1[k][0] = Whh1[2 * k]; whh1[k][1] = Whh1[2 * k + 1];
        bias1[k]   = bih1[k] + bhh1[k];
    }

    // Initial state (inputs are [LAYERS, B, H])
    float h0a = h0in[2 * bb],             h0b = h0in[2 * bb + 1];
    float c0a = c0in[2 * bb],             c0b = c0in[2 * bb + 1];
    float h1a = h0in[2 * BATCH + 2 * bb], h1b = h0in[2 * BATCH + 2 * bb + 1];
    float c1a = c0in[2 * BATCH + 2 * bb], c1b = c0in[2 * BATCH + 2 * bb + 1];

    const float4* __restrict__ xp = (const float4*)xg;

    // depth-4 software pipeline on the per-step gate loads (32 B/step)
    float4 plo[4], phi[4];
#pragma unroll
    for (int t = 0; t < 4; ++t) {
        plo[t] = xp[(t * BATCH + bb) * 2];
        phi[t] = xp[(t * BATCH + bb) * 2 + 1];
    }

    // Layer-1 partial gates (h1-dependent half), hoisted across steps.
    float p[H4];
#pragma unroll
    for (int k = 0; k < H4; ++k)
        p[k] = bias1[k] + h1a * whh1[k][0] + h1b * whh1[k][1];

#pragma unroll 4
    for (int t = 0; t < T_STEPS; ++t) {
        int s = t & 3;
        float4 l4 = plo[s], h4 = phi[s];
        if (t + 4 < T_STEPS) {
            plo[s] = xp[((t + 4) * BATCH + bb) * 2];
            phi[s] = xp[((t + 4) * BATCH + bb) * 2 + 1];
        }
        float xv[H4] = {l4.x, l4.y, l4.z, l4.w, h4.x, h4.y, h4.z, h4.w};

        // ----- layer 0: gates = xg + h @ Whh0^T (pairs: i i f f g g o o) ---
        float gt[H4];
#pragma unroll
        for (int k = 0; k < H4; ++k)
            gt[k] = xv[k] + h0a * whh0[k][0] + h0b * whh0[k][1];
        c0a = sigf(gt[2]) * c0a + sigf(gt[0]) * tanhfast(gt[4]);
        c0b = sigf(gt[3]) * c0b + sigf(gt[1]) * tanhfast(gt[5]);
        h0a = sigf(gt[6]) * tanhfast(c0a);
        h0b = sigf(gt[7]) * tanhfast(c0b);

        // ----- layer 1: q = p (precomputed) + h0-dependent half ------------
        float qt[H4];
#pragma unroll
        for (int k = 0; k < H4; ++k)
            qt[k] = p[k] + h0a * wih1[k][0] + h0b * wih1[k][1];
        c1a = sigf(qt[2]) * c1a + sigf(qt[0]) * tanhfast(qt[4]);
        c1b = sigf(qt[3]) * c1b + sigf(qt[1]) * tanhfast(qt[5]);
        h1a = sigf(qt[6]) * tanhfast(c1a);
        h1b = sigf(qt[7]) * tanhfast(c1b);

        // hoist next step's h1-dependent layer-1 partials
#pragma unroll
        for (int k = 0; k < H4; ++k)
            p[k] = bias1[k] + h1a * whh1[k][0] + h1b * whh1[k][1];
    }

    if (active)
        out[b] = h1a * Wlin[0] + h1b * Wlin[1] + blin[0];
}

extern "C" void kernel_launch(void* const* d_in, const int* in_sizes, int n_in,
                              void* d_out, int out_size, void* d_ws, size_t ws_size,
                              hipStream_t stream) {
    const float* x      = (const float*)d_in[0];
    const float* h0     = (const float*)d_in[1];
    const float* c0     = (const float*)d_in[2];
    const float* W_ih0  = (const float*)d_in[3];
    const float* W_hh0  = (const float*)d_in[4];
    const float* b_ih0  = (const float*)d_in[5];
    const float* b_hh0  = (const float*)d_in[6];
    const float* W_ih1  = (const float*)d_in[7];
    const float* W_hh1  = (const float*)d_in[8];
    const float* b_ih1  = (const float*)d_in[9];
    const float* b_hh1  = (const float*)d_in[10];
    const float* W_lin  = (const float*)d_in[11];
    const float* b_lin  = (const float*)d_in[12];
    float* out = (float*)d_out;
    float* xg  = (float*)d_ws;   // T*B*8 floats = 8.192 MB

    const int rows = T_STEPS * BATCH;                 // 256000
    xproj_kernel<<<rows / ROWS_PER_BLK, 256, 0, stream>>>(x, W_ih0, b_ih0, b_hh0, xg);
    lstm_seq_kernel<<<(BATCH + 63) / 64, 64, 0, stream>>>(
        xg, h0, c0, W_hh0, W_ih1, W_hh1, b_ih1, b_hh1, W_lin, b_lin, out);
}